// Round 1
// baseline (249.120 us; speedup 1.0000x reference)
//
#include <hip/hip_runtime.h>
#include <hip/hip_bf16.h>

// DotProductAttention (Swin windowed, masked softmax).
// Inputs are FP32 (per reference/harness; proven by rounds 1&4 bf16-only NaN
// vs rounds 2&3 dual-path pass + round-3 WRITE_SIZE=73MB ~ fp32 output).
// n=1024, Q=K=256, d=32, num_windows=64, NUM_HEADS=8.
// Block = (window w, q-tile qt, batch-quarter qr): 1024 blocks x 4 batches.
//  - mask fragment: fp32 loaded once/block, packed bf16 in 32 VGPRs
//  - K,V staged per batch into LDS as bf16 (coalesced float4 + cvt_pk);
//    V transposed so PV A-frags are ds_read_b128
//  - S^T = K*Q^T orientation: mask regs contiguous, softmax = 2 shuffles
//  - P transpose + O bounce ALIAS the dead K region (barrier after S reads)
//    -> LDS 37.4 KB -> 4 blocks/CU possible
//  - O via LDS bounce -> dense 2 KB/wave dwordx4 stores (fp32 out)
//  - XCD swizzle: all 16 blocks of a window on one XCD (mask/K/V L2 reuse)
// R5 de-spill: prior build spilled ~25 arch VGPRs/thread (VGPR_Count=64:
//  acc[16]=64 AGPRs left only 64 arch under launch_bounds(256,4)=128 budget;
//  WRITE_SIZE 115.7MB vs 32MB output = scratch dirty-evictions).
//  (a) pk[16] eliminated: exp in place in acc, pack bf16 at LDS-write time
//  (b) __launch_bounds__(256,3): allocator cap 170 -> headroom, no spill.

typedef __attribute__((ext_vector_type(8))) short short8;   // 8 bf16 = 4 VGPR
typedef __attribute__((ext_vector_type(4))) float floatx4;  // MFMA C/D

#define KSTRIDE 40    // ushorts per K row (32 + 8 pad; 80 B, mult of 16)
#define VSTRIDE 264   // ushorts per Vt row (256 + 8 pad; 528 B, mult of 16)
#define PSTRIDE 136   // ushorts per P row (128 + 8 pad; 272 B, mult of 16)
#define OSTRIDE 36    // floats per O-bounce row (32 + 4 pad; 144 B, mult of 16)
#define NEGV -1000000.0f

#define LDS_FENCE() __asm__ volatile("s_waitcnt lgkmcnt(0)" ::: "memory")

static __device__ __forceinline__ float u2f_lo(unsigned u) {
    union { unsigned u; float f; } x; x.u = u << 16; return x.f;
}
static __device__ __forceinline__ float u2f_hi(unsigned u) {
    union { unsigned u; float f; } x; x.u = u & 0xffff0000u; return x.f;
}
static __device__ __forceinline__ unsigned packbf2(float a, float b) {
    union { __hip_bfloat162 h2; unsigned u; } x;
    x.h2 = __float22bfloat162_rn(make_float2(a, b));   // hw v_cvt_pk_bf16_f32
    return x.u;
}

union S8U { short8 s8; unsigned u[4]; };

__global__ __launch_bounds__(256, 3)
void attn_swin_kernel(const float* __restrict__ Qg,
                      const float* __restrict__ Kg,
                      const float* __restrict__ Vg,
                      const int* __restrict__ VLg,
                      const float* __restrict__ Wg,
                      float* __restrict__ Og)
{
    __shared__ __align__(16) unsigned short Ksh[256 * KSTRIDE]; // 20.0 KB (aliased: P + O bounce)
    __shared__ __align__(16) unsigned short Vt[32 * VSTRIDE];   // 16.5 KB  V^T: Vt[d][k]

    const int tid  = threadIdx.x;
    const int wave = tid >> 6;
    const int lane = tid & 63;
    const int c    = lane & 15;   // MFMA column (= q within wave's 16 rows)
    const int quad = lane >> 4;   // 0..3

    // blk -> (w, qt, qr) with all 16 blocks of window w sharing blk%8 (XCD)
    const int blk = blockIdx.x;
    const int xx  = blk & 7;
    const int yy  = blk >> 3;           // 0..127
    const int w   = xx + 8 * (yy & 7);  // 0..63
    const int zz  = yy >> 3;            // 0..15
    const int qt  = zz & 3;
    const int qr  = zz >> 2;            // 0..3
    const int b0  = (qr >> 1) * 512 + w * 8 + (qr & 1) * 4;   // 4 batches b0..b0+3
    const int qbase = qt * 64 + wave * 16;

    // valid_lens dtype probe (values in [1,256]): int64 layout => word 1 == 0
    const bool vl64 = (VLg[1] == 0);
    auto read_vl = [&](int b) -> int {
        int v = vl64 ? (int)(((const long long*)VLg)[b]) : VLg[b];
        return min(max(v, 0), 256);
    };

    // ---- window-mask fragment: fp32 load once, packed bf16 in 32 VGPRs ----
    uint2 mraw[16];
    {
        const float* wp = Wg + (size_t)w * 65536 + (size_t)(qbase + c) * 256 + quad * 4;
        #pragma unroll
        for (int t = 0; t < 16; ++t) {
            float4 m = *(const float4*)(wp + t * 16);
            mraw[t].x = packbf2(m.x, m.y);
            mraw[t].y = packbf2(m.z, m.w);
        }
    }

    const float scale = 0.17677669529663687f;  // 1/sqrt(32)
    unsigned short* const pw = &Ksh[wave * 2560];   // wave-private 5120 B alias slice

    for (int i = 0; i < 4; ++i) {
        const int b      = b0 + i;
        const int vl     = read_vl(b);
        const int used16 = (vl + 15) >> 4;
        const int used32 = (vl + 31) >> 5;
        const int tmax   = used32 * 2;
        const size_t bb  = (size_t)b * 8192;

        __syncthreads();   // A: all waves done with LDS (P/O alias, Vt) of batch i-1

        // ---- stage K (row-major) + V (transposed) as bf16; coalesced loads ----
        {
            const int r0 = tid >> 3;          // row within 32-row chunk
            const int d0 = (tid & 7) * 4;     // first of 4 d's this thread converts
            const float* kp = Kg + bb + tid * 4;
            const float* vp = Vg + bb + tid * 4;
            for (int ch = 0; ch < used32; ++ch) {
                float4 kf = *(const float4*)(kp + ch * 1024);
                float4 vf = *(const float4*)(vp + ch * 1024);
                const int row = ch * 32 + r0;
                uint2 kk;
                kk.x = packbf2(kf.x, kf.y);
                kk.y = packbf2(kf.z, kf.w);
                *(uint2*)&Ksh[row * KSTRIDE + d0] = kk;     // ds_write_b64
                unsigned v0 = packbf2(vf.x, vf.y);
                unsigned v1 = packbf2(vf.z, vf.w);
                Vt[(d0 + 0) * VSTRIDE + row] = (unsigned short)(v0 & 0xffffu);
                Vt[(d0 + 1) * VSTRIDE + row] = (unsigned short)(v0 >> 16);
                Vt[(d0 + 2) * VSTRIDE + row] = (unsigned short)(v1 & 0xffffu);
                Vt[(d0 + 3) * VSTRIDE + row] = (unsigned short)(v1 >> 16);
            }
        }
        __syncthreads();   // B: staging visible

        // ---- Q B-frag: fp32 -> packed bf16 ----
        short8 qb;
        {
            const float* qp = Qg + bb + (size_t)(qbase + c) * 32 + quad * 8;
            float4 q0 = *(const float4*)qp;
            float4 q1 = *(const float4*)(qp + 4);
            S8U t;
            t.u[0] = packbf2(q0.x, q0.y);
            t.u[1] = packbf2(q0.z, q0.w);
            t.u[2] = packbf2(q1.x, q1.y);
            t.u[3] = packbf2(q1.z, q1.w);
            qb = t.s8;
        }

        // ---- S^T = K*Q^T (A-frags from LDS) ----
        floatx4 acc[16];
        #pragma unroll
        for (int t = 0; t < 16; ++t) {
            if (t < used16) {
                short8 ka = *(const short8*)&Ksh[(t * 16 + c) * KSTRIDE + quad * 8];
                floatx4 z = {0.f, 0.f, 0.f, 0.f};
                acc[t] = __builtin_amdgcn_mfma_f32_16x16x32_bf16(ka, qb, z, 0, 0, 0);
            }
        }

        // ---- scale + register mask + valid-len; per-lane max ----
        float mx = -3.0e38f;
        #pragma unroll
        for (int t = 0; t < 16; ++t) {
            if (t < used16) {
                float m0 = u2f_lo(mraw[t].x), m1 = u2f_hi(mraw[t].x);
                float m2 = u2f_lo(mraw[t].y), m3 = u2f_hi(mraw[t].y);
                float s0 = fmaf(acc[t][0], scale, m0);
                float s1 = fmaf(acc[t][1], scale, m1);
                float s2 = fmaf(acc[t][2], scale, m2);
                float s3 = fmaf(acc[t][3], scale, m3);
                if ((t + 1) * 16 > vl) {             // boundary tile only
                    const int k0 = t * 16 + quad * 4;
                    s0 = (k0 + 0 < vl) ? s0 : NEGV;
                    s1 = (k0 + 1 < vl) ? s1 : NEGV;
                    s2 = (k0 + 2 < vl) ? s2 : NEGV;
                    s3 = (k0 + 3 < vl) ? s3 : NEGV;
                }
                acc[t][0] = s0; acc[t][1] = s1; acc[t][2] = s2; acc[t][3] = s3;
                mx = fmaxf(mx, fmaxf(fmaxf(s0, s1), fmaxf(s2, s3)));
            }
        }
        mx = fmaxf(mx, __shfl_xor(mx, 16));
        mx = fmaxf(mx, __shfl_xor(mx, 32));

        // ---- exp + sum IN PLACE (no pk[] regs; pack happens at LDS write) ----
        float l = 0.f;
        #pragma unroll
        for (int t = 0; t < 16; ++t) {
            if (t < used16) {
                float p0 = __expf(acc[t][0] - mx);
                float p1 = __expf(acc[t][1] - mx);
                float p2 = __expf(acc[t][2] - mx);
                float p3 = __expf(acc[t][3] - mx);
                l += (p0 + p1) + (p2 + p3);
                acc[t][0] = p0; acc[t][1] = p1; acc[t][2] = p2; acc[t][3] = p3;
            }
        }
        l += __shfl_xor(l, 16);
        l += __shfl_xor(l, 32);
        const float rl = (l > 0.f) ? (1.0f / l) : 0.f;

        __syncthreads();   // C: all waves done reading Ksh -> safe to alias with P/O

        // ---- PV in two k-halves through wave-private alias slice ----
        floatx4 o0 = {0.f, 0.f, 0.f, 0.f}, o1 = {0.f, 0.f, 0.f, 0.f};

        #pragma unroll
        for (int t = 0; t < 8; ++t) {
            if (t < used16) {
                uint2 pp;
                pp.x = packbf2(acc[t][0], acc[t][1]);
                pp.y = packbf2(acc[t][2], acc[t][3]);
                *(uint2*)&pw[c * PSTRIDE + t * 16 + quad * 4] = pp;
            } else if (t < tmax) {
                uint2 z; z.x = 0u; z.y = 0u;
                *(uint2*)&pw[c * PSTRIDE + t * 16 + quad * 4] = z;
            }
        }
        LDS_FENCE();
        #pragma unroll
        for (int kt = 0; kt < 4; ++kt) {
            if (kt < used32) {
                short8 pb  = *(const short8*)&pw[c * PSTRIDE + kt * 32 + quad * 8];
                short8 va0 = *(const short8*)&Vt[c * VSTRIDE + kt * 32 + quad * 8];
                short8 va1 = *(const short8*)&Vt[(16 + c) * VSTRIDE + kt * 32 + quad * 8];
                o0 = __builtin_amdgcn_mfma_f32_16x16x32_bf16(va0, pb, o0, 0, 0, 0);
                o1 = __builtin_amdgcn_mfma_f32_16x16x32_bf16(va1, pb, o1, 0, 0, 0);
            }
        }
        if (used32 > 4) {
            #pragma unroll
            for (int t = 8; t < 16; ++t) {
                if (t < used16) {
                    uint2 pp;
                    pp.x = packbf2(acc[t][0], acc[t][1]);
                    pp.y = packbf2(acc[t][2], acc[t][3]);
                    *(uint2*)&pw[c * PSTRIDE + (t - 8) * 16 + quad * 4] = pp;
                } else if (t < tmax) {
                    uint2 z; z.x = 0u; z.y = 0u;
                    *(uint2*)&pw[c * PSTRIDE + (t - 8) * 16 + quad * 4] = z;
                }
            }
            LDS_FENCE();
            #pragma unroll
            for (int kt = 4; kt < 8; ++kt) {
                if (kt < used32) {
                    short8 pb  = *(const short8*)&pw[c * PSTRIDE + (kt - 4) * 32 + quad * 8];
                    short8 va0 = *(const short8*)&Vt[c * VSTRIDE + kt * 32 + quad * 8];
                    short8 va1 = *(const short8*)&Vt[(16 + c) * VSTRIDE + kt * 32 + quad * 8];
                    o0 = __builtin_amdgcn_mfma_f32_16x16x32_bf16(va0, pb, o0, 0, 0, 0);
                    o1 = __builtin_amdgcn_mfma_f32_16x16x32_bf16(va1, pb, o1, 0, 0, 0);
                }
            }
        }

        // ---- normalize; bounce O through alias slice -> dense fp32 stores ----
        {
            float* ow = (float*)pw;   // stride OSTRIDE floats
            LDS_FENCE();              // compiler fence: P reads before O writes
            float4 w0, w1;
            w0.x = o0[0] * rl; w0.y = o0[1] * rl; w0.z = o0[2] * rl; w0.w = o0[3] * rl;
            w1.x = o1[0] * rl; w1.y = o1[1] * rl; w1.z = o1[2] * rl; w1.w = o1[3] * rl;
            *(float4*)&ow[c * OSTRIDE + quad * 4]      = w0;   // d = quad*4..+3
            *(float4*)&ow[c * OSTRIDE + 16 + quad * 4] = w1;   // d = 16+quad*4..+3
            LDS_FENCE();              // O writes visible before reads
            const int qq = lane >> 2, seg = lane & 3;
            float4 r0 = *(const float4*)&ow[qq * OSTRIDE + seg * 8];
            float4 r1 = *(const float4*)&ow[qq * OSTRIDE + seg * 8 + 4];
            float* op = Og + bb + (size_t)(qbase + qq) * 32 + seg * 8;
            *(float4*)op       = r0;   // wave covers 2 KiB dense
            *(float4*)(op + 4) = r1;
        }
    }
}

extern "C" void kernel_launch(void* const* d_in, const int* in_sizes, int n_in,
                              void* d_out, int out_size, void* d_ws, size_t ws_size,
                              hipStream_t stream) {
    (void)in_sizes; (void)n_in; (void)out_size; (void)d_ws; (void)ws_size;
    const float* Qg  = (const float*)d_in[0];
    const float* Kg  = (const float*)d_in[1];
    const float* Vg  = (const float*)d_in[2];
    const int*   VLg = (const int*)d_in[3];
    const float* Wg  = (const float*)d_in[4];
    float*       Og  = (float*)d_out;

    attn_swin_kernel<<<dim3(1024), dim3(256), 0, stream>>>(Qg, Kg, Vg, VLg, Wg, Og);
}